// Round 14
// baseline (272.983 us; speedup 1.0000x reference)
//
#include <hip/hip_runtime.h>
#include <hip/hip_bf16.h>
#include <stdint.h>

#define B_    2
#define S_    4096
#define DM_   2048
#define H_    16
#define D_    128
#define M_TOT (B_ * S_)     // 8192
#define N_TOT (3 * DM_)     // 6144
#define K_TOT DM_           // 2048

typedef __attribute__((ext_vector_type(8)))  short short8;
typedef __attribute__((ext_vector_type(16))) float f32x16;
typedef unsigned short ushort_t;

__device__ __forceinline__ unsigned short f2bf(float f) {
    union { float f; unsigned u; } u; u.f = f;
    unsigned r = u.u + 0x7fffu + ((u.u >> 16) & 1u);
    return (unsigned short)(r >> 16);
}
__device__ __forceinline__ float bf2f(unsigned short s) {
    union { unsigned u; float f; } u; u.u = ((unsigned)s) << 16;
    return u.f;
}

__device__ __forceinline__ void gload_lds16(const void* g, void* l) {
    __builtin_amdgcn_global_load_lds(
        (const __attribute__((address_space(1))) void*)g,
        (__attribute__((address_space(3))) void*)l,
        16, 0, 0);
}

// ------------- fused cast fp32->bf16: x,Wq,Wk,Wv -> one contiguous dst -----
__global__ void cast_all(const float* __restrict__ x,  const float* __restrict__ Wq,
                         const float* __restrict__ Wk, const float* __restrict__ Wv,
                         unsigned short* __restrict__ dst) {
    const int NX = (M_TOT * K_TOT) / 4;   // 4,194,304 float4s
    const int NW = (DM_ * DM_) / 4;       // 1,048,576
    const int NT = NX + 3 * NW;           // 7,340,032
    int i = blockIdx.x * blockDim.x + threadIdx.x;
    const int stride = gridDim.x * blockDim.x;
    for (; i < NT; i += stride) {
        const float4* src; int j;
        if (i < NX)              { src = (const float4*)x;  j = i; }
        else if (i < NX + NW)    { src = (const float4*)Wq; j = i - NX; }
        else if (i < NX + 2*NW)  { src = (const float4*)Wk; j = i - NX - NW; }
        else                     { src = (const float4*)Wv; j = i - NX - 2*NW; }
        float4 v = src[j];
        ushort4 o;
        o.x = f2bf(v.x); o.y = f2bf(v.y); o.z = f2bf(v.z); o.w = f2bf(v.w);
        ((ushort4*)dst)[i] = o;
    }
}

// ---------------- QKV GEMM: R11 skeleton + 32x32x16 MFMA -------------------
// C[M][N] = A[M][K] * B[N][K]^T (+bias), bf16 in, bf16 out.
// 512 thr = 8 waves (2M x 4N); per-wave output 128x64 = 4x2 frags of 32x32.
// LDS: 2 buffers x (A[256][64] + B[256][64]) bf16 = 128 KiB, st_16x32 swizzle
// — staging, vmcnt ledger, barrier placement BYTE-IDENTICAL to R11 (proven
// 54.5% / 175us). Only the compute shape changes: 32 mfma_32x32x16 per
// K-tile per wave (vs 64 16x16x32) = 20% fewer MFMA-pipe cycles (m119: 32.3
// cy vs 2x19.4 cy per 32k FLOP).
// Fragment lane maps (generalize the verified 16x16 maps):
//   A/B operand: row/col = lane&31, k0 = (lane>>5)*8  (8 contiguous k)
//   C/D:         col = lane&31, row = (reg&3)+8*(reg>>2)+4*(lane>>5) [m101]
// Read regions == R11 staging groups: a1 = rowblks {wm*8+0..3} (G1),
// a2 = {wm*8+4..7} (G4), b0 = {wn*4+0,1} (G2), b1 = {wn*4+2,3} (G3).
//   P1: rd a1(8),b0(4) | st G4(T+1) | 8 mfma a1xb0  | bar
//   P2: rd b1(4)       | st G1(T+2) | 8 mfma a1xb1  | bar
//   P3: rd a2(8)       | st G2(T+2) | 8 mfma a2xb0  | bar
//   P4:                | st G3(T+2) | 8 mfma a2xb1  | vmcnt(6) | bar

#define BKT   64
#define NKT   (K_TOT / BKT)   // 32 K-tiles
#define ABUF  16384           // ushort offset of B-tile within a buffer
#define BUF1  32768           // ushort offset of buffer 1

#define PB() do { asm volatile("" ::: "memory");                               \
                  __builtin_amdgcn_s_barrier();                                \
                  asm volatile("" ::: "memory"); } while (0)
#define VM6()   asm volatile("s_waitcnt vmcnt(6)" ::: "memory")
#define VM0()   asm volatile("s_waitcnt vmcnt(0)" ::: "memory")
#define SP1()   __builtin_amdgcn_s_setprio(1)
#define SP0()   __builtin_amdgcn_s_setprio(0)
#define NOSTAGE do {} while (0)
#define NOVM    do {} while (0)

// stage one 16x64 LDS block (2 gload_lds) of A or B at k-offset K0
#define STAGE_A(BO, K0, ABLK) do {                                              \
    const ushort_t* s_ = aStage + (size_t)(ABLK) * (16 * K_TOT) + (K0);         \
    gload_lds16(s_,      &lds[(BO) + (ABLK) * 1024]);                           \
    gload_lds16(s_ + 32, &lds[(BO) + (ABLK) * 1024 + 512]);                     \
} while (0)
#define STAGE_B(BO, K0, BBLK) do {                                              \
    const ushort_t* s_ = bStage + (size_t)(BBLK) * (16 * K_TOT) + (K0);         \
    gload_lds16(s_,      &lds[(BO) + ABUF + (BBLK) * 1024]);                    \
    gload_lds16(s_ + 32, &lds[(BO) + ABUF + (BBLK) * 1024 + 512]);              \
} while (0)

// A frag (mb, ks): rowblk = wm*8 + mb*2 + lsub; subtile = (ks>>1); inner by ks&1
#define READ_A32(DST, MB0, BO) do { _Pragma("unroll")                           \
    for (int mb = 0; mb < 2; ++mb) { _Pragma("unroll")                          \
    for (int ks = 0; ks < 4; ++ks)                                              \
        DST[mb][ks] = *(const short8*)&lds[(BO) +                               \
            (wm * 8 + ((MB0) + mb) * 2 + lsub) * 1024 + (ks >> 1) * 512 +       \
            ((ks & 1) ? innerK1 : innerK0)];                                    \
    } } while (0)

#define READ_B32(DST, NB, BO) do { _Pragma("unroll")                            \
    for (int ks = 0; ks < 4; ++ks)                                              \
        DST[ks] = *(const short8*)&lds[(BO) + ABUF +                            \
            (wn * 4 + (NB) * 2 + lsub) * 1024 + (ks >> 1) * 512 +               \
            ((ks & 1) ? innerK1 : innerK0)];                                    \
    } while (0)

// 8 MFMA: ks outer, mb inner -> 2 independent acc chains, dep distance 2
#define MQ32(AR, MB0, BR, NB) do { _Pragma("unroll")                            \
    for (int ks = 0; ks < 4; ++ks) { _Pragma("unroll")                          \
    for (int mb = 0; mb < 2; ++mb)                                              \
        acc[(MB0) + mb][NB] = __builtin_amdgcn_mfma_f32_32x32x16_bf16(          \
            AR[mb][ks], BR[ks], acc[(MB0) + mb][NB], 0, 0, 0);                  \
    } } while (0)

#define KTILE(BO, S1, S2, S3, S4, VM_STMT) do {                                 \
    /* P1 */ READ_A32(a1, 0, BO); READ_B32(b0, 0, BO); S1;                      \
    SP1(); MQ32(a1, 0, b0, 0); SP0(); PB();                                     \
    /* P2 */ READ_B32(b1, 1, BO); S2;                                           \
    SP1(); MQ32(a1, 0, b1, 1); SP0(); PB();                                     \
    /* P3 */ READ_A32(a2, 2, BO); S3;                                           \
    SP1(); MQ32(a2, 2, b0, 0); SP0(); PB();                                     \
    /* P4 */ S4;                                                                \
    SP1(); MQ32(a2, 2, b1, 1); SP0(); VM_STMT; PB();                            \
} while (0)

__global__ __launch_bounds__(512, 2) void gemm_qkv(
    const ushort_t* __restrict__ A,   // [M_TOT][K_TOT] bf16
    const ushort_t* __restrict__ Bm,  // [N_TOT][K_TOT] bf16 (Wq;Wk;Wv)
    const float* __restrict__ bq, const float* __restrict__ bk,
    const float* __restrict__ bv,
    ushort_t* __restrict__ C)         // [M_TOT][N_TOT] bf16
{
    __shared__ __align__(16) ushort_t lds[65536];   // 128 KiB

    // XCD-aware bijective swizzle (768 % 8 == 0)
    const int nwg = gridDim.x;                  // 768
    const int cpx = nwg >> 3;                   // 96
    const int bid = blockIdx.x;
    const int swz = (bid & 7) * cpx + (bid >> 3);
    const int ntile = N_TOT / 256;              // 24
    const int tm = swz / ntile;
    const int tn = swz % ntile;
    const int tmRow = tm * 256, tnRow = tn * 256;

    const int tid  = threadIdx.x;
    const int w    = tid >> 6;
    const int lane = tid & 63;
    const int wm   = w >> 2, wn = w & 3;        // 2 x 4 wave grid

    // staging block groups (identical to R11): G1=wA, G4=wA+4, G2=wB, G3=wB+2
    const int wA = w + (w & 4);
    const int wB = ((w >> 1) << 2) | (w & 1);

    // staging source (inverse-swizzle): lane L -> row L>>2, col ((L&3)*8)^((L>>5)<<4)
    const int rL     = lane >> 2;
    const int cSwzSt = ((lane & 3) * 8) ^ (((lane >> 5) & 1) << 4);
    const ushort_t* aStage = A  + (size_t)(tmRow + rL) * K_TOT + cSwzSt;
    const ushort_t* bStage = Bm + (size_t)(tnRow + rL) * K_TOT + cSwzSt;

    // 32x32 fragment read offsets: row = lane&31 (lsub picks 16-row subtile),
    // k0 = (lane>>5)*8 within 16-k step; swizzle bit from row&8
    const int lsub   = (lane >> 4) & 1;
    const int swzb   = (lane & 8) << 1;                 // 16 if row&8
    const int innerK0 = (lane & 15) * 32 + (((lane >> 5) * 8)      ^ swzb);
    const int innerK1 = (lane & 15) * 32 + ((16 + (lane >> 5) * 8) ^ swzb);

    f32x16 acc[4][2] = {};
    short8 a1[2][4], a2[2][4], b0[4], b1[4];

    // prologue: tile0 G1-G4 -> buf0; tile1 G1,G2,G3 -> buf1 (G4(1) at T0.P1).
    STAGE_A(0, 0, wA);  STAGE_B(0, 0, wB);  STAGE_B(0, 0, wB + 2);  STAGE_A(0, 0, wA + 4);
    STAGE_A(BUF1, BKT, wA); STAGE_B(BUF1, BKT, wB); STAGE_B(BUF1, BKT, wB + 2);
    VM6();
    PB();

    // steady loop: tiles 0..29 (staging schedule identical to R11)
    for (int kt = 0; kt < NKT - 2; kt += 2) {
        KTILE(0,
              STAGE_A(BUF1, (size_t)(kt + 1) * BKT, wA + 4),   // G4(T+1)
              STAGE_A(0,    (size_t)(kt + 2) * BKT, wA),       // G1(T+2)
              STAGE_B(0,    (size_t)(kt + 2) * BKT, wB),       // G2(T+2)
              STAGE_B(0,    (size_t)(kt + 2) * BKT, wB + 2),   // G3(T+2)
              VM6());
        KTILE(BUF1,
              STAGE_A(0,    (size_t)(kt + 2) * BKT, wA + 4),   // G4(T+2)
              STAGE_A(BUF1, (size_t)(kt + 3) * BKT, wA),       // G1(T+3)
              STAGE_B(BUF1, (size_t)(kt + 3) * BKT, wB),       // G2(T+3)
              STAGE_B(BUF1, (size_t)(kt + 3) * BKT, wB + 2),   // G3(T+3)
              VM6());
    }
    // epilogue tiles 30/31
    KTILE(0,
          STAGE_A(BUF1, (size_t)(NKT - 1) * BKT, wA + 4),      // G4(31)
          NOSTAGE, NOSTAGE, NOSTAGE,
          VM0());
    KTILE(BUF1, NOSTAGE, NOSTAGE, NOSTAGE, NOSTAGE, NOVM);

    // ---- epilogue: repack through LDS for coalesced 16B stores ----
    // per m-block (32 rows x 64 cols): scatter bf16(acc+bias) via C/D map
    // row=(reg&3)+8*(reg>>2)+4*(lane>>5), col=lane&31; read back row-major.
    {
        ushort_t* ldsW = &lds[w * 2304];        // 32 rows x stride 72
        const int colBase = tnRow + wn * 64;
        const float* bias = (colBase < 2048) ? bq : (colBase < 4096) ? bk : bv;
        const int rowBase = tmRow + wm * 128;
        float bval[2];
#pragma unroll
        for (int nb = 0; nb < 2; ++nb)
            bval[nb] = bias[(colBase + nb * 32 + (lane & 31)) & 2047];
        const int rbase = 4 * (lane >> 5);
#pragma unroll
        for (int mb = 0; mb < 4; ++mb) {
#pragma unroll
            for (int nb = 0; nb < 2; ++nb)
#pragma unroll
                for (int r = 0; r < 16; ++r) {
                    const int row32 = (r & 3) + 8 * (r >> 2) + rbase;
                    ldsW[row32 * 72 + nb * 32 + (lane & 31)] =
                        f2bf(acc[mb][nb][r] + bval[nb]);
                }
            asm volatile("s_waitcnt lgkmcnt(0)" ::: "memory");  // writes -> readable
#pragma unroll
            for (int pass = 0; pass < 4; ++pass) {
                const int row = pass * 8 + (lane >> 3);
                short8 v = *(const short8*)&ldsW[row * 72 + (lane & 7) * 8];
                *(short8*)&C[(size_t)(rowBase + mb * 32 + row) * N_TOT +
                             colBase + (lane & 7) * 8] = v;
            }
            asm volatile("s_waitcnt lgkmcnt(0)" ::: "memory");  // reads done before next mb
        }
    }
}

// ---------------- per-position heads-attention ----------------
#define LSTR 132   // padded fp32 row stride (breaks stride-128 bank conflicts)

__global__ __launch_bounds__(256) void attn_kernel(
    const ushort_t* __restrict__ QKV,  // [M_TOT][N_TOT] bf16
    float* __restrict__ out)           // [B][S][DM] fp32, scattered layout
{
    __shared__ __align__(16) float Qs[H_ * LSTR];
    __shared__ __align__(16) float Ks[H_ * LSTR];
    __shared__ __align__(16) float Vs[H_ * LSTR];

    const int pos = blockIdx.x;
    const int b   = pos >> 12;
    const int s   = pos & 4095;
    const int tid = threadIdx.x;
    const int lane = tid & 63;
    const ushort_t* row = QKV + (size_t)pos * N_TOT;

    {
        const int r  = tid >> 4;
        const int d0 = (tid & 15) * 8;
        short8 q = *(const short8*)(row +        r * 128 + d0);
        short8 k = *(const short8*)(row + 2048 + r * 128 + d0);
        short8 v = *(const short8*)(row + 4096 + r * 128 + d0);
#pragma unroll
        for (int j = 0; j < 8; ++j) {
            Qs[r * LSTR + d0 + j] = bf2f((unsigned short)q[j]);
            Ks[r * LSTR + d0 + j] = bf2f((unsigned short)k[j]);
            Vs[r * LSTR + d0 + j] = bf2f((unsigned short)v[j]);
        }
    }
    __syncthreads();

    const int h = tid >> 4;
    const int t = tid & 15;
    float sc = 0.f;
    {
        const float* qp = &Qs[h * LSTR];
        const float* kp = &Ks[t * LSTR];
#pragma unroll
        for (int d = 0; d < 128; d += 4) {
            float4 qv = *(const float4*)(qp + d);
            float4 kv = *(const float4*)(kp + d);
            sc += qv.x * kv.x + qv.y * kv.y + qv.z * kv.z + qv.w * kv.w;
        }
    }
    sc *= 0.08838834764831845f;   // 1/sqrt(128)

    float mx = sc;
#pragma unroll
    for (int o = 1; o < 16; o <<= 1) mx = fmaxf(mx, __shfl_xor(mx, o, 64));
    float e = __expf(sc - mx);
    float sm = e;
#pragma unroll
    for (int o = 1; o < 16; o <<= 1) sm += __shfl_xor(sm, o, 64);
    const float attn = e / sm;

    float o8[8] = {0.f, 0.f, 0.f, 0.f, 0.f, 0.f, 0.f, 0.f};
#pragma unroll
    for (int tt = 0; tt < 16; ++tt) {
        const float aw = __shfl(attn, (lane & 48) | tt, 64);
        const float* vp = &Vs[tt * LSTR + t * 8];
        float4 v0 = *(const float4*)(vp);
        float4 v1 = *(const float4*)(vp + 4);
        o8[0] += aw * v0.x; o8[1] += aw * v0.y; o8[2] += aw * v0.z; o8[3] += aw * v0.w;
        o8[4] += aw * v1.x; o8[5] += aw * v1.y; o8[6] += aw * v1.z; o8[7] += aw * v1.w;
    }

    const int orow = h * 256 + (s >> 4);
    const int ocol = (s & 15) * 128 + t * 8;
    float* op = out + ((size_t)b * S_ + orow) * DM_ + ocol;
    float4 w0 = { o8[0], o8[1], o8[2], o8[3] };
    float4 w1 = { o8[4], o8[5], o8[6], o8[7] };
    *(float4*)(op)     = w0;
    *(float4*)(op + 4) = w1;
}

// ---------------- launch ----------------
extern "C" void kernel_launch(void* const* d_in, const int* in_sizes, int n_in,
                              void* d_out, int out_size, void* d_ws, size_t ws_size,
                              hipStream_t stream) {
    const float* x  = (const float*)d_in[0];
    const float* Wq = (const float*)d_in[1];
    const float* bq = (const float*)d_in[2];
    const float* Wk = (const float*)d_in[3];
    const float* bk = (const float*)d_in[4];
    const float* Wv = (const float*)d_in[5];
    const float* bv = (const float*)d_in[6];
    float* out = (float*)d_out;

    char* ws = (char*)d_ws;
    unsigned short* xb  = (unsigned short*)ws;                       // 33,554,432 B
    unsigned short* Wb  = (unsigned short*)(ws + 33554432);          // 25,165,824 B
    unsigned short* qkv = (unsigned short*)(ws + 58720256);          // 100,663,296 B

    cast_all<<<2048, 256, 0, stream>>>(x, Wq, Wk, Wv, xb);           // xb + Wb contiguous

    gemm_qkv<<<(M_TOT / 256) * (N_TOT / 256), 512, 0, stream>>>(xb, Wb, bq, bk, bv, qkv);

    attn_kernel<<<M_TOT, 256, 0, stream>>>(qkv, out);
}

// Round 15
// 272.587 us; speedup vs baseline: 1.0015x; 1.0015x over previous
//
#include <hip/hip_runtime.h>
#include <hip/hip_bf16.h>
#include <stdint.h>

#define B_    2
#define S_    4096
#define DM_   2048
#define H_    16
#define D_    128
#define M_TOT (B_ * S_)     // 8192
#define N_TOT (3 * DM_)     // 6144
#define K_TOT DM_           // 2048

typedef __attribute__((ext_vector_type(8)))  short short8;
typedef __attribute__((ext_vector_type(16))) float f32x16;
typedef unsigned short ushort_t;

__device__ __forceinline__ unsigned short f2bf(float f) {
    union { float f; unsigned u; } u; u.f = f;
    unsigned r = u.u + 0x7fffu + ((u.u >> 16) & 1u);
    return (unsigned short)(r >> 16);
}
__device__ __forceinline__ float bf2f(unsigned short s) {
    union { unsigned u; float f; } u; u.u = ((unsigned)s) << 16;
    return u.f;
}

__device__ __forceinline__ void gload_lds16(const void* g, void* l) {
    __builtin_amdgcn_global_load_lds(
        (const __attribute__((address_space(1))) void*)g,
        (__attribute__((address_space(3))) void*)l,
        16, 0, 0);
}

// ------------- fused cast fp32->bf16: x,Wq,Wk,Wv -> one contiguous dst -----
__global__ void cast_all(const float* __restrict__ x,  const float* __restrict__ Wq,
                         const float* __restrict__ Wk, const float* __restrict__ Wv,
                         unsigned short* __restrict__ dst) {
    const int NX = (M_TOT * K_TOT) / 4;   // 4,194,304 float4s
    const int NW = (DM_ * DM_) / 4;       // 1,048,576
    const int NT = NX + 3 * NW;           // 7,340,032
    int i = blockIdx.x * blockDim.x + threadIdx.x;
    const int stride = gridDim.x * blockDim.x;
    for (; i < NT; i += stride) {
        const float4* src; int j;
        if (i < NX)              { src = (const float4*)x;  j = i; }
        else if (i < NX + NW)    { src = (const float4*)Wq; j = i - NX; }
        else if (i < NX + 2*NW)  { src = (const float4*)Wk; j = i - NX - NW; }
        else                     { src = (const float4*)Wv; j = i - NX - 2*NW; }
        float4 v = src[j];
        ushort4 o;
        o.x = f2bf(v.x); o.y = f2bf(v.y); o.z = f2bf(v.z); o.w = f2bf(v.w);
        ((ushort4*)dst)[i] = o;
    }
}

// ---------------- QKV GEMM: R11 skeleton + 32x32x16 MFMA + parity swizzle --
// C[M][N] = A[M][K] * B[N][K]^T (+bias), bf16 in, bf16 out.
// 512 thr = 8 waves (2M x 4N); per-wave output 128x64 = 4x2 frags of 32x32.
// LDS: 2 buffers x (A[256][64] + B[256][64]) bf16 = 128 KiB, st_16x32 swizzle
// + NEW parity swizzle: odd-parity subtile blocks XOR bit4 (16 ushorts=32B)
// into the in-subtile column. WHY: the 32x32 operand map has only 2 distinct
// k-columns/wave (lane>>5) and lsub's two rowblks are 2048B apart (bank-
// identical) -> R14 measured 1.93e7 bank conflicts (~4-way on every read,
// m136: 1.58x). Parity XOR restores all 4 byte-columns -> free 2-way.
// Both-sides-or-neither (rule 21): read innerK ^= lsub<<4; staging source
// cSwzSt ^= (w&1)<<4 (each wave stages only parity w&1 blocks: wA, wA+4,
// wB, wB+2 all have parity w&1 — verified).
// Schedule/ledger byte-identical to R11 (proven):
//   P1: rd a1(8),b0(4) | st G4(T+1) | 8 mfma a1xb0  | bar
//   P2: rd b1(4)       | st G1(T+2) | 8 mfma a1xb1  | bar
//   P3: rd a2(8)       | st G2(T+2) | 8 mfma a2xb0  | bar
//   P4:                | st G3(T+2) | 8 mfma a2xb1  | vmcnt(6) | bar

#define BKT   64
#define NKT   (K_TOT / BKT)   // 32 K-tiles
#define ABUF  16384           // ushort offset of B-tile within a buffer
#define BUF1  32768           // ushort offset of buffer 1

#define PB() do { asm volatile("" ::: "memory");                               \
                  __builtin_amdgcn_s_barrier();                                \
                  asm volatile("" ::: "memory"); } while (0)
#define VM6()   asm volatile("s_waitcnt vmcnt(6)" ::: "memory")
#define VM0()   asm volatile("s_waitcnt vmcnt(0)" ::: "memory")
#define SP1()   __builtin_amdgcn_s_setprio(1)
#define SP0()   __builtin_amdgcn_s_setprio(0)
#define NOSTAGE do {} while (0)
#define NOVM    do {} while (0)

// stage one 16x64 LDS block (2 gload_lds) of A or B at k-offset K0
#define STAGE_A(BO, K0, ABLK) do {                                              \
    const ushort_t* s_ = aStage + (size_t)(ABLK) * (16 * K_TOT) + (K0);         \
    gload_lds16(s_,      &lds[(BO) + (ABLK) * 1024]);                           \
    gload_lds16(s_ + 32, &lds[(BO) + (ABLK) * 1024 + 512]);                     \
} while (0)
#define STAGE_B(BO, K0, BBLK) do {                                              \
    const ushort_t* s_ = bStage + (size_t)(BBLK) * (16 * K_TOT) + (K0);         \
    gload_lds16(s_,      &lds[(BO) + ABUF + (BBLK) * 1024]);                    \
    gload_lds16(s_ + 32, &lds[(BO) + ABUF + (BBLK) * 1024 + 512]);              \
} while (0)

// A frag (mb, ks): rowblk = wm*8 + mb*2 + lsub; subtile = (ks>>1); inner by ks&1
#define READ_A32(DST, MB0, BO) do { _Pragma("unroll")                           \
    for (int mb = 0; mb < 2; ++mb) { _Pragma("unroll")                          \
    for (int ks = 0; ks < 4; ++ks)                                              \
        DST[mb][ks] = *(const short8*)&lds[(BO) +                               \
            (wm * 8 + ((MB0) + mb) * 2 + lsub) * 1024 + (ks >> 1) * 512 +       \
            ((ks & 1) ? innerK1 : innerK0)];                                    \
    } } while (0)

#define READ_B32(DST, NB, BO) do { _Pragma("unroll")                            \
    for (int ks = 0; ks < 4; ++ks)                                              \
        DST[ks] = *(const short8*)&lds[(BO) + ABUF +                            \
            (wn * 4 + (NB) * 2 + lsub) * 1024 + (ks >> 1) * 512 +               \
            ((ks & 1) ? innerK1 : innerK0)];                                    \
    } while (0)

// 8 MFMA: ks outer, mb inner -> 2 independent acc chains, dep distance 2
#define MQ32(AR, MB0, BR, NB) do { _Pragma("unroll")                            \
    for (int ks = 0; ks < 4; ++ks) { _Pragma("unroll")                          \
    for (int mb = 0; mb < 2; ++mb)                                              \
        acc[(MB0) + mb][NB] = __builtin_amdgcn_mfma_f32_32x32x16_bf16(          \
            AR[mb][ks], BR[ks], acc[(MB0) + mb][NB], 0, 0, 0);                  \
    } } while (0)

#define KTILE(BO, S1, S2, S3, S4, VM_STMT) do {                                 \
    /* P1 */ READ_A32(a1, 0, BO); READ_B32(b0, 0, BO); S1;                      \
    SP1(); MQ32(a1, 0, b0, 0); SP0(); PB();                                     \
    /* P2 */ READ_B32(b1, 1, BO); S2;                                           \
    SP1(); MQ32(a1, 0, b1, 1); SP0(); PB();                                     \
    /* P3 */ READ_A32(a2, 2, BO); S3;                                           \
    SP1(); MQ32(a2, 2, b0, 0); SP0(); PB();                                     \
    /* P4 */ S4;                                                                \
    SP1(); MQ32(a2, 2, b1, 1); SP0(); VM_STMT; PB();                            \
} while (0)

__global__ __launch_bounds__(512, 2) void gemm_qkv(
    const ushort_t* __restrict__ A,   // [M_TOT][K_TOT] bf16
    const ushort_t* __restrict__ Bm,  // [N_TOT][K_TOT] bf16 (Wq;Wk;Wv)
    const float* __restrict__ bq, const float* __restrict__ bk,
    const float* __restrict__ bv,
    ushort_t* __restrict__ C)         // [M_TOT][N_TOT] bf16
{
    __shared__ __align__(16) ushort_t lds[65536];   // 128 KiB

    // XCD-aware bijective swizzle (768 % 8 == 0)
    const int nwg = gridDim.x;                  // 768
    const int cpx = nwg >> 3;                   // 96
    const int bid = blockIdx.x;
    const int swz = (bid & 7) * cpx + (bid >> 3);
    const int ntile = N_TOT / 256;              // 24
    const int tm = swz / ntile;
    const int tn = swz % ntile;
    const int tmRow = tm * 256, tnRow = tn * 256;

    const int tid  = threadIdx.x;
    const int w    = tid >> 6;
    const int lane = tid & 63;
    const int wm   = w >> 2, wn = w & 3;        // 2 x 4 wave grid

    // staging block groups (identical to R11): G1=wA, G4=wA+4, G2=wB, G3=wB+2
    // all four blocks of wave w have parity (w&1).
    const int wA = w + (w & 4);
    const int wB = ((w >> 1) << 2) | (w & 1);

    // staging source (inverse-swizzle + parity bit): lane L -> row L>>2,
    // col ((L&3)*8) ^ ((L>>5)<<4) ^ ((w&1)<<4)
    const int rL     = lane >> 2;
    const int cSwzSt = (((lane & 3) * 8) ^ ((lane >> 5) << 4)) ^ ((w & 1) << 4);
    const ushort_t* aStage = A  + (size_t)(tmRow + rL) * K_TOT + cSwzSt;
    const ushort_t* bStage = Bm + (size_t)(tnRow + rL) * K_TOT + cSwzSt;

    // 32x32 fragment read offsets: row = lane&31 (lsub = subtile block),
    // k0 = (lane>>5)*8; XORs: st_16x32 swizzle (row&8) + parity (lsub)
    const int lsub    = (lane >> 4) & 1;
    const int swzb    = (lane & 8) << 1;                // 16 if row&8
    const int psw     = lsub << 4;                      // parity bank-shift
    const int innerK0 = (lane & 15) * 32 + ((((lane >> 5) * 8)      ^ swzb) ^ psw);
    const int innerK1 = (lane & 15) * 32 + (((16 + (lane >> 5) * 8) ^ swzb) ^ psw);

    f32x16 acc[4][2] = {};
    short8 a1[2][4], a2[2][4], b0[4], b1[4];

    // prologue: tile0 G1-G4 -> buf0; tile1 G1,G2,G3 -> buf1 (G4(1) at T0.P1).
    STAGE_A(0, 0, wA);  STAGE_B(0, 0, wB);  STAGE_B(0, 0, wB + 2);  STAGE_A(0, 0, wA + 4);
    STAGE_A(BUF1, BKT, wA); STAGE_B(BUF1, BKT, wB); STAGE_B(BUF1, BKT, wB + 2);
    VM6();
    PB();

    // steady loop: tiles 0..29 (staging schedule identical to R11)
    for (int kt = 0; kt < NKT - 2; kt += 2) {
        KTILE(0,
              STAGE_A(BUF1, (size_t)(kt + 1) * BKT, wA + 4),   // G4(T+1)
              STAGE_A(0,    (size_t)(kt + 2) * BKT, wA),       // G1(T+2)
              STAGE_B(0,    (size_t)(kt + 2) * BKT, wB),       // G2(T+2)
              STAGE_B(0,    (size_t)(kt + 2) * BKT, wB + 2),   // G3(T+2)
              VM6());
        KTILE(BUF1,
              STAGE_A(0,    (size_t)(kt + 2) * BKT, wA + 4),   // G4(T+2)
              STAGE_A(BUF1, (size_t)(kt + 3) * BKT, wA),       // G1(T+3)
              STAGE_B(BUF1, (size_t)(kt + 3) * BKT, wB),       // G2(T+3)
              STAGE_B(BUF1, (size_t)(kt + 3) * BKT, wB + 2),   // G3(T+3)
              VM6());
    }
    // epilogue tiles 30/31
    KTILE(0,
          STAGE_A(BUF1, (size_t)(NKT - 1) * BKT, wA + 4),      // G4(31)
          NOSTAGE, NOSTAGE, NOSTAGE,
          VM0());
    KTILE(BUF1, NOSTAGE, NOSTAGE, NOSTAGE, NOSTAGE, NOVM);

    // ---- epilogue: repack through LDS for coalesced 16B stores ----
    // per m-block (32 rows x 64 cols): scatter bf16(acc+bias) via C/D map
    // row=(reg&3)+8*(reg>>2)+4*(lane>>5), col=lane&31; read back row-major.
    {
        ushort_t* ldsW = &lds[w * 2304];        // 32 rows x stride 72
        const int colBase = tnRow + wn * 64;
        const float* bias = (colBase < 2048) ? bq : (colBase < 4096) ? bk : bv;
        const int rowBase = tmRow + wm * 128;
        float bval[2];
#pragma unroll
        for (int nb = 0; nb < 2; ++nb)
            bval[nb] = bias[(colBase + nb * 32 + (lane & 31)) & 2047];
        const int rbase = 4 * (lane >> 5);
#pragma unroll
        for (int mb = 0; mb < 4; ++mb) {
#pragma unroll
            for (int nb = 0; nb < 2; ++nb)
#pragma unroll
                for (int r = 0; r < 16; ++r) {
                    const int row32 = (r & 3) + 8 * (r >> 2) + rbase;
                    ldsW[row32 * 72 + nb * 32 + (lane & 31)] =
                        f2bf(acc[mb][nb][r] + bval[nb]);
                }
            asm volatile("s_waitcnt lgkmcnt(0)" ::: "memory");  // writes -> readable
#pragma unroll
            for (int pass = 0; pass < 4; ++pass) {
                const int row = pass * 8 + (lane >> 3);
                short8 v = *(const short8*)&ldsW[row * 72 + (lane & 7) * 8];
                *(short8*)&C[(size_t)(rowBase + mb * 32 + row) * N_TOT +
                             colBase + (lane & 7) * 8] = v;
            }
            asm volatile("s_waitcnt lgkmcnt(0)" ::: "memory");  // reads done before next mb
        }
    }
}

// ---------------- per-position heads-attention ----------------
#define LSTR 132   // padded fp32 row stride (breaks stride-128 bank conflicts)

__global__ __launch_bounds__(256) void attn_kernel(
    const ushort_t* __restrict__ QKV,  // [M_TOT][N_TOT] bf16
    float* __restrict__ out)           // [B][S][DM] fp32, scattered layout
{
    __shared__ __align__(16) float Qs[H_ * LSTR];
    __shared__ __align__(16) float Ks[H_ * LSTR];
    __shared__ __align__(16) float Vs[H_ * LSTR];

    const int pos = blockIdx.x;
    const int b   = pos >> 12;
    const int s   = pos & 4095;
    const int tid = threadIdx.x;
    const int lane = tid & 63;
    const ushort_t* row = QKV + (size_t)pos * N_TOT;

    {
        const int r  = tid >> 4;
        const int d0 = (tid & 15) * 8;
        short8 q = *(const short8*)(row +        r * 128 + d0);
        short8 k = *(const short8*)(row + 2048 + r * 128 + d0);
        short8 v = *(const short8*)(row + 4096 + r * 128 + d0);
#pragma unroll
        for (int j = 0; j < 8; ++j) {
            Qs[r * LSTR + d0 + j] = bf2f((unsigned short)q[j]);
            Ks[r * LSTR + d0 + j] = bf2f((unsigned short)k[j]);
            Vs[r * LSTR + d0 + j] = bf2f((unsigned short)v[j]);
        }
    }
    __syncthreads();

    const int h = tid >> 4;
    const int t = tid & 15;
    float sc = 0.f;
    {
        const float* qp = &Qs[h * LSTR];
        const float* kp = &Ks[t * LSTR];
#pragma unroll
        for (int d = 0; d < 128; d += 4) {
            float4 qv = *(const float4*)(qp + d);
            float4 kv = *(const float4*)(kp + d);
            sc += qv.x * kv.x + qv.y * kv.y + qv.z * kv.z + qv.w * kv.w;
        }
    }
    sc *= 0.08838834764831845f;   // 1/sqrt(128)

    float mx = sc;
#pragma unroll
    for (int o = 1; o < 16; o <<= 1) mx = fmaxf(mx, __shfl_xor(mx, o, 64));
    float e = __expf(sc - mx);
    float sm = e;
#pragma unroll
    for (int o = 1; o < 16; o <<= 1) sm += __shfl_xor(sm, o, 64);
    const float attn = e / sm;

    float o8[8] = {0.f, 0.f, 0.f, 0.f, 0.f, 0.f, 0.f, 0.f};
#pragma unroll
    for (int tt = 0; tt < 16; ++tt) {
        const float aw = __shfl(attn, (lane & 48) | tt, 64);
        const float* vp = &Vs[tt * LSTR + t * 8];
        float4 v0 = *(const float4*)(vp);
        float4 v1 = *(const float4*)(vp + 4);
        o8[0] += aw * v0.x; o8[1] += aw * v0.y; o8[2] += aw * v0.z; o8[3] += aw * v0.w;
        o8[4] += aw * v1.x; o8[5] += aw * v1.y; o8[6] += aw * v1.z; o8[7] += aw * v1.w;
    }

    const int orow = h * 256 + (s >> 4);
    const int ocol = (s & 15) * 128 + t * 8;
    float* op = out + ((size_t)b * S_ + orow) * DM_ + ocol;
    float4 w0 = { o8[0], o8[1], o8[2], o8[3] };
    float4 w1 = { o8[4], o8[5], o8[6], o8[7] };
    *(float4*)(op)     = w0;
    *(float4*)(op + 4) = w1;
}

// ---------------- launch ----------------
extern "C" void kernel_launch(void* const* d_in, const int* in_sizes, int n_in,
                              void* d_out, int out_size, void* d_ws, size_t ws_size,
                              hipStream_t stream) {
    const float* x  = (const float*)d_in[0];
    const float* Wq = (const float*)d_in[1];
    const float* bq = (const float*)d_in[2];
    const float* Wk = (const float*)d_in[3];
    const float* bk = (const float*)d_in[4];
    const float* Wv = (const float*)d_in[5];
    const float* bv = (const float*)d_in[6];
    float* out = (float*)d_out;

    char* ws = (char*)d_ws;
    unsigned short* xb  = (unsigned short*)ws;                       // 33,554,432 B
    unsigned short* Wb  = (unsigned short*)(ws + 33554432);          // 25,165,824 B
    unsigned short* qkv = (unsigned short*)(ws + 58720256);          // 100,663,296 B

    cast_all<<<2048, 256, 0, stream>>>(x, Wq, Wk, Wv, xb);           // xb + Wb contiguous

    gemm_qkv<<<(M_TOT / 256) * (N_TOT / 256), 512, 0, stream>>>(xb, Wb, bq, bk, bv, qkv);

    attn_kernel<<<M_TOT, 256, 0, stream>>>(qkv, out);
}

// Round 16
// 253.571 us; speedup vs baseline: 1.0766x; 1.0750x over previous
//
#include <hip/hip_runtime.h>
#include <hip/hip_bf16.h>
#include <stdint.h>

#define B_    2
#define S_    4096
#define DM_   2048
#define H_    16
#define D_    128
#define M_TOT (B_ * S_)     // 8192
#define N_TOT (3 * DM_)     // 6144
#define K_TOT DM_           // 2048

typedef __attribute__((ext_vector_type(8)))  short short8;
typedef __attribute__((ext_vector_type(16))) float f32x16;
typedef unsigned short ushort_t;

__device__ __forceinline__ unsigned short f2bf(float f) {
    union { float f; unsigned u; } u; u.f = f;
    unsigned r = u.u + 0x7fffu + ((u.u >> 16) & 1u);
    return (unsigned short)(r >> 16);
}
__device__ __forceinline__ float bf2f(unsigned short s) {
    union { unsigned u; float f; } u; u.u = ((unsigned)s) << 16;
    return u.f;
}

__device__ __forceinline__ void gload_lds16(const void* g, void* l) {
    __builtin_amdgcn_global_load_lds(
        (const __attribute__((address_space(1))) void*)g,
        (__attribute__((address_space(3))) void*)l,
        16, 0, 0);
}

// ------------- fused cast fp32->bf16: x,Wq,Wk,Wv -> one contiguous dst -----
__global__ void cast_all(const float* __restrict__ x,  const float* __restrict__ Wq,
                         const float* __restrict__ Wk, const float* __restrict__ Wv,
                         unsigned short* __restrict__ dst) {
    const int NX = (M_TOT * K_TOT) / 4;   // 4,194,304 float4s
    const int NW = (DM_ * DM_) / 4;       // 1,048,576
    const int NT = NX + 3 * NW;           // 7,340,032
    int i = blockIdx.x * blockDim.x + threadIdx.x;
    const int stride = gridDim.x * blockDim.x;
    for (; i < NT; i += stride) {
        const float4* src; int j;
        if (i < NX)              { src = (const float4*)x;  j = i; }
        else if (i < NX + NW)    { src = (const float4*)Wq; j = i - NX; }
        else if (i < NX + 2*NW)  { src = (const float4*)Wk; j = i - NX - NW; }
        else                     { src = (const float4*)Wv; j = i - NX - 2*NW; }
        float4 v = src[j];
        ushort4 o;
        o.x = f2bf(v.x); o.y = f2bf(v.y); o.z = f2bf(v.z); o.w = f2bf(v.w);
        ((ushort4*)dst)[i] = o;
    }
}

// ---------------- QKV GEMM: R11 skeleton + 32x32x16 MFMA + 4-dword parity --
// C[M][N] = A[M][K] * B[N][K]^T (+bias), bf16 in, bf16 out.
// 512 thr = 8 waves (2M x 4N); per-wave output 128x64 = 4x2 frags of 32x32.
// LDS: 2 buffers x (A[256][64] + B[256][64]) bf16 = 128 KiB.
// BANK FIX v2 (R15's v1 was a no-op — exact math): read span-starts are
// dword%32 = 16(r&1) + col/2 with col ∈ {0,16} ushorts -> set {0,8,16,24};
// XOR by 16 ushorts (8 dwords) PERMUTES WITHIN that set (conflicts bit-
// identical, 1.927e7). Correct shift is 8 ushorts = 4 dwords: odd-parity
// rowblocks then start at {4,20,12,28} -> 8 span-starts x 4 lanes per
// half-wave, matching the measured-clean 16x16 distribution exactly.
// Both sides (rule 21): read innerK ^= lsub<<3; staging src ^= (w&1)<<3
// (wave w stages only parity-(w&1) blocks: wA, wA+4, wB, wB+2 — verified).
// Schedule/ledger byte-identical to R11 (proven):
//   P1: rd a1(8),b0(4) | st G4(T+1) | 8 mfma a1xb0  | bar
//   P2: rd b1(4)       | st G1(T+2) | 8 mfma a1xb1  | bar
//   P3: rd a2(8)       | st G2(T+2) | 8 mfma a2xb0  | bar
//   P4:                | st G3(T+2) | 8 mfma a2xb1  | vmcnt(6) | bar

#define BKT   64
#define NKT   (K_TOT / BKT)   // 32 K-tiles
#define ABUF  16384           // ushort offset of B-tile within a buffer
#define BUF1  32768           // ushort offset of buffer 1

#define PB() do { asm volatile("" ::: "memory");                               \
                  __builtin_amdgcn_s_barrier();                                \
                  asm volatile("" ::: "memory"); } while (0)
#define VM6()   asm volatile("s_waitcnt vmcnt(6)" ::: "memory")
#define VM0()   asm volatile("s_waitcnt vmcnt(0)" ::: "memory")
#define SP1()   __builtin_amdgcn_s_setprio(1)
#define SP0()   __builtin_amdgcn_s_setprio(0)
#define NOSTAGE do {} while (0)
#define NOVM    do {} while (0)

// stage one 16x64 LDS block (2 gload_lds) of A or B at k-offset K0
#define STAGE_A(BO, K0, ABLK) do {                                              \
    const ushort_t* s_ = aStage + (size_t)(ABLK) * (16 * K_TOT) + (K0);         \
    gload_lds16(s_,      &lds[(BO) + (ABLK) * 1024]);                           \
    gload_lds16(s_ + 32, &lds[(BO) + (ABLK) * 1024 + 512]);                     \
} while (0)
#define STAGE_B(BO, K0, BBLK) do {                                              \
    const ushort_t* s_ = bStage + (size_t)(BBLK) * (16 * K_TOT) + (K0);         \
    gload_lds16(s_,      &lds[(BO) + ABUF + (BBLK) * 1024]);                    \
    gload_lds16(s_ + 32, &lds[(BO) + ABUF + (BBLK) * 1024 + 512]);              \
} while (0)

// A frag (mb, ks): rowblk = wm*8 + mb*2 + lsub; subtile = (ks>>1); inner by ks&1
#define READ_A32(DST, MB0, BO) do { _Pragma("unroll")                           \
    for (int mb = 0; mb < 2; ++mb) { _Pragma("unroll")                          \
    for (int ks = 0; ks < 4; ++ks)                                              \
        DST[mb][ks] = *(const short8*)&lds[(BO) +                               \
            (wm * 8 + ((MB0) + mb) * 2 + lsub) * 1024 + (ks >> 1) * 512 +       \
            ((ks & 1) ? innerK1 : innerK0)];                                    \
    } } while (0)

#define READ_B32(DST, NB, BO) do { _Pragma("unroll")                            \
    for (int ks = 0; ks < 4; ++ks)                                              \
        DST[ks] = *(const short8*)&lds[(BO) + ABUF +                            \
            (wn * 4 + (NB) * 2 + lsub) * 1024 + (ks >> 1) * 512 +               \
            ((ks & 1) ? innerK1 : innerK0)];                                    \
    } while (0)

// 8 MFMA: ks outer, mb inner -> 2 independent acc chains, dep distance 2
#define MQ32(AR, MB0, BR, NB) do { _Pragma("unroll")                            \
    for (int ks = 0; ks < 4; ++ks) { _Pragma("unroll")                          \
    for (int mb = 0; mb < 2; ++mb)                                              \
        acc[(MB0) + mb][NB] = __builtin_amdgcn_mfma_f32_32x32x16_bf16(          \
            AR[mb][ks], BR[ks], acc[(MB0) + mb][NB], 0, 0, 0);                  \
    } } while (0)

#define KTILE(BO, S1, S2, S3, S4, VM_STMT) do {                                 \
    /* P1 */ READ_A32(a1, 0, BO); READ_B32(b0, 0, BO); S1;                      \
    SP1(); MQ32(a1, 0, b0, 0); SP0(); PB();                                     \
    /* P2 */ READ_B32(b1, 1, BO); S2;                                           \
    SP1(); MQ32(a1, 0, b1, 1); SP0(); PB();                                     \
    /* P3 */ READ_A32(a2, 2, BO); S3;                                           \
    SP1(); MQ32(a2, 2, b0, 0); SP0(); PB();                                     \
    /* P4 */ S4;                                                                \
    SP1(); MQ32(a2, 2, b1, 1); SP0(); VM_STMT; PB();                            \
} while (0)

__global__ __launch_bounds__(512, 2) void gemm_qkv(
    const ushort_t* __restrict__ A,   // [M_TOT][K_TOT] bf16
    const ushort_t* __restrict__ Bm,  // [N_TOT][K_TOT] bf16 (Wq;Wk;Wv)
    const float* __restrict__ bq, const float* __restrict__ bk,
    const float* __restrict__ bv,
    ushort_t* __restrict__ C)         // [M_TOT][N_TOT] bf16
{
    __shared__ __align__(16) ushort_t lds[65536];   // 128 KiB

    // XCD-aware bijective swizzle (768 % 8 == 0)
    const int nwg = gridDim.x;                  // 768
    const int cpx = nwg >> 3;                   // 96
    const int bid = blockIdx.x;
    const int swz = (bid & 7) * cpx + (bid >> 3);
    const int ntile = N_TOT / 256;              // 24
    const int tm = swz / ntile;
    const int tn = swz % ntile;
    const int tmRow = tm * 256, tnRow = tn * 256;

    const int tid  = threadIdx.x;
    const int w    = tid >> 6;
    const int lane = tid & 63;
    const int wm   = w >> 2, wn = w & 3;        // 2 x 4 wave grid

    // staging block groups (identical to R11): G1=wA, G4=wA+4, G2=wB, G3=wB+2
    // all four blocks of wave w have parity (w&1).
    const int wA = w + (w & 4);
    const int wB = ((w >> 1) << 2) | (w & 1);

    // staging source (inverse-swizzle + 4-dword parity): lane L -> row L>>2,
    // col ((L&3)*8) ^ ((L>>5)<<4) ^ ((w&1)<<3)
    const int rL     = lane >> 2;
    const int cSwzSt = (((lane & 3) * 8) ^ ((lane >> 5) << 4)) ^ ((w & 1) << 3);
    const ushort_t* aStage = A  + (size_t)(tmRow + rL) * K_TOT + cSwzSt;
    const ushort_t* bStage = Bm + (size_t)(tnRow + rL) * K_TOT + cSwzSt;

    // 32x32 fragment read offsets: row = lane&31 (lsub = subtile block),
    // k0 = (lane>>5)*8; XORs: st_16x32 swizzle (row&8) + 8-ushort parity (lsub)
    const int lsub    = (lane >> 4) & 1;
    const int swzb    = (lane & 8) << 1;                // 16 ushorts if row&8
    const int psw     = lsub << 3;                      // 8 ushorts = 4 dwords
    const int innerK0 = (lane & 15) * 32 + ((((lane >> 5) * 8)      ^ swzb) ^ psw);
    const int innerK1 = (lane & 15) * 32 + (((16 + (lane >> 5) * 8) ^ swzb) ^ psw);

    f32x16 acc[4][2] = {};
    short8 a1[2][4], a2[2][4], b0[4], b1[4];

    // prologue: tile0 G1-G4 -> buf0; tile1 G1,G2,G3 -> buf1 (G4(1) at T0.P1).
    STAGE_A(0, 0, wA);  STAGE_B(0, 0, wB);  STAGE_B(0, 0, wB + 2);  STAGE_A(0, 0, wA + 4);
    STAGE_A(BUF1, BKT, wA); STAGE_B(BUF1, BKT, wB); STAGE_B(BUF1, BKT, wB + 2);
    VM6();
    PB();

    // steady loop: tiles 0..29 (staging schedule identical to R11)
    for (int kt = 0; kt < NKT - 2; kt += 2) {
        KTILE(0,
              STAGE_A(BUF1, (size_t)(kt + 1) * BKT, wA + 4),   // G4(T+1)
              STAGE_A(0,    (size_t)(kt + 2) * BKT, wA),       // G1(T+2)
              STAGE_B(0,    (size_t)(kt + 2) * BKT, wB),       // G2(T+2)
              STAGE_B(0,    (size_t)(kt + 2) * BKT, wB + 2),   // G3(T+2)
              VM6());
        KTILE(BUF1,
              STAGE_A(0,    (size_t)(kt + 2) * BKT, wA + 4),   // G4(T+2)
              STAGE_A(BUF1, (size_t)(kt + 3) * BKT, wA),       // G1(T+3)
              STAGE_B(BUF1, (size_t)(kt + 3) * BKT, wB),       // G2(T+3)
              STAGE_B(BUF1, (size_t)(kt + 3) * BKT, wB + 2),   // G3(T+3)
              VM6());
    }
    // epilogue tiles 30/31
    KTILE(0,
          STAGE_A(BUF1, (size_t)(NKT - 1) * BKT, wA + 4),      // G4(31)
          NOSTAGE, NOSTAGE, NOSTAGE,
          VM0());
    KTILE(BUF1, NOSTAGE, NOSTAGE, NOSTAGE, NOSTAGE, NOVM);

    // ---- epilogue: repack through LDS for coalesced 16B stores ----
    // per m-block (32 rows x 64 cols): scatter bf16(acc+bias) via C/D map
    // row=(reg&3)+8*(reg>>2)+4*(lane>>5), col=lane&31; read back row-major.
    {
        ushort_t* ldsW = &lds[w * 2304];        // 32 rows x stride 72
        const int colBase = tnRow + wn * 64;
        const float* bias = (colBase < 2048) ? bq : (colBase < 4096) ? bk : bv;
        const int rowBase = tmRow + wm * 128;
        float bval[2];
#pragma unroll
        for (int nb = 0; nb < 2; ++nb)
            bval[nb] = bias[(colBase + nb * 32 + (lane & 31)) & 2047];
        const int rbase = 4 * (lane >> 5);
#pragma unroll
        for (int mb = 0; mb < 4; ++mb) {
#pragma unroll
            for (int nb = 0; nb < 2; ++nb)
#pragma unroll
                for (int r = 0; r < 16; ++r) {
                    const int row32 = (r & 3) + 8 * (r >> 2) + rbase;
                    ldsW[row32 * 72 + nb * 32 + (lane & 31)] =
                        f2bf(acc[mb][nb][r] + bval[nb]);
                }
            asm volatile("s_waitcnt lgkmcnt(0)" ::: "memory");  // writes -> readable
#pragma unroll
            for (int pass = 0; pass < 4; ++pass) {
                const int row = pass * 8 + (lane >> 3);
                short8 v = *(const short8*)&ldsW[row * 72 + (lane & 7) * 8];
                *(short8*)&C[(size_t)(rowBase + mb * 32 + row) * N_TOT +
                             colBase + (lane & 7) * 8] = v;
            }
            asm volatile("s_waitcnt lgkmcnt(0)" ::: "memory");  // reads done before next mb
        }
    }
}

// ---------------- per-position heads-attention ----------------
#define LSTR 132   // padded fp32 row stride (breaks stride-128 bank conflicts)

__global__ __launch_bounds__(256) void attn_kernel(
    const ushort_t* __restrict__ QKV,  // [M_TOT][N_TOT] bf16
    float* __restrict__ out)           // [B][S][DM] fp32, scattered layout
{
    __shared__ __align__(16) float Qs[H_ * LSTR];
    __shared__ __align__(16) float Ks[H_ * LSTR];
    __shared__ __align__(16) float Vs[H_ * LSTR];

    const int pos = blockIdx.x;
    const int b   = pos >> 12;
    const int s   = pos & 4095;
    const int tid = threadIdx.x;
    const int lane = tid & 63;
    const ushort_t* row = QKV + (size_t)pos * N_TOT;

    {
        const int r  = tid >> 4;
        const int d0 = (tid & 15) * 8;
        short8 q = *(const short8*)(row +        r * 128 + d0);
        short8 k = *(const short8*)(row + 2048 + r * 128 + d0);
        short8 v = *(const short8*)(row + 4096 + r * 128 + d0);
#pragma unroll
        for (int j = 0; j < 8; ++j) {
            Qs[r * LSTR + d0 + j] = bf2f((unsigned short)q[j]);
            Ks[r * LSTR + d0 + j] = bf2f((unsigned short)k[j]);
            Vs[r * LSTR + d0 + j] = bf2f((unsigned short)v[j]);
        }
    }
    __syncthreads();

    const int h = tid >> 4;
    const int t = tid & 15;
    float sc = 0.f;
    {
        const float* qp = &Qs[h * LSTR];
        const float* kp = &Ks[t * LSTR];
#pragma unroll
        for (int d = 0; d < 128; d += 4) {
            float4 qv = *(const float4*)(qp + d);
            float4 kv = *(const float4*)(kp + d);
            sc += qv.x * kv.x + qv.y * kv.y + qv.z * kv.z + qv.w * kv.w;
        }
    }
    sc *= 0.08838834764831845f;   // 1/sqrt(128)

    float mx = sc;
#pragma unroll
    for (int o = 1; o < 16; o <<= 1) mx = fmaxf(mx, __shfl_xor(mx, o, 64));
    float e = __expf(sc - mx);
    float sm = e;
#pragma unroll
    for (int o = 1; o < 16; o <<= 1) sm += __shfl_xor(sm, o, 64);
    const float attn = e / sm;

    float o8[8] = {0.f, 0.f, 0.f, 0.f, 0.f, 0.f, 0.f, 0.f};
#pragma unroll
    for (int tt = 0; tt < 16; ++tt) {
        const float aw = __shfl(attn, (lane & 48) | tt, 64);
        const float* vp = &Vs[tt * LSTR + t * 8];
        float4 v0 = *(const float4*)(vp);
        float4 v1 = *(const float4*)(vp + 4);
        o8[0] += aw * v0.x; o8[1] += aw * v0.y; o8[2] += aw * v0.z; o8[3] += aw * v0.w;
        o8[4] += aw * v1.x; o8[5] += aw * v1.y; o8[6] += aw * v1.z; o8[7] += aw * v1.w;
    }

    const int orow = h * 256 + (s >> 4);
    const int ocol = (s & 15) * 128 + t * 8;
    float* op = out + ((size_t)b * S_ + orow) * DM_ + ocol;
    float4 w0 = { o8[0], o8[1], o8[2], o8[3] };
    float4 w1 = { o8[4], o8[5], o8[6], o8[7] };
    *(float4*)(op)     = w0;
    *(float4*)(op + 4) = w1;
}

// ---------------- launch ----------------
extern "C" void kernel_launch(void* const* d_in, const int* in_sizes, int n_in,
                              void* d_out, int out_size, void* d_ws, size_t ws_size,
                              hipStream_t stream) {
    const float* x  = (const float*)d_in[0];
    const float* Wq = (const float*)d_in[1];
    const float* bq = (const float*)d_in[2];
    const float* Wk = (const float*)d_in[3];
    const float* bk = (const float*)d_in[4];
    const float* Wv = (const float*)d_in[5];
    const float* bv = (const float*)d_in[6];
    float* out = (float*)d_out;

    char* ws = (char*)d_ws;
    unsigned short* xb  = (unsigned short*)ws;                       // 33,554,432 B
    unsigned short* Wb  = (unsigned short*)(ws + 33554432);          // 25,165,824 B
    unsigned short* qkv = (unsigned short*)(ws + 58720256);          // 100,663,296 B

    cast_all<<<2048, 256, 0, stream>>>(x, Wq, Wk, Wv, xb);           // xb + Wb contiguous

    gemm_qkv<<<(M_TOT / 256) * (N_TOT / 256), 512, 0, stream>>>(xb, Wb, bq, bk, bv, qkv);

    attn_kernel<<<M_TOT, 256, 0, stream>>>(qkv, out);
}